// Round 5
// baseline (298.564 us; speedup 1.0000x reference)
//
#include <hip/hip_runtime.h>
#include <math.h>

#define EPS_Q 1e-8f

typedef float vfloat4 __attribute__((ext_vector_type(4)));
typedef int   vint4   __attribute__((ext_vector_type(4)));

struct F3 { float x, y, z; };
struct Q4 { F3 v; float w; };

__device__ __forceinline__ F3 add3(F3 a, F3 b){ return {a.x+b.x, a.y+b.y, a.z+b.z}; }
__device__ __forceinline__ F3 sub3(F3 a, F3 b){ return {a.x-b.x, a.y-b.y, a.z-b.z}; }
__device__ __forceinline__ F3 scal3(float s, F3 a){ return {s*a.x, s*a.y, s*a.z}; }
__device__ __forceinline__ float dot3(F3 a, F3 b){ return a.x*b.x + a.y*b.y + a.z*b.z; }
__device__ __forceinline__ F3 cross3(F3 a, F3 b){
    return { a.y*b.z - a.z*b.y, a.z*b.x - a.x*b.z, a.x*b.y - a.y*b.x };
}
__device__ __forceinline__ Q4 qmul(Q4 q, Q4 r){
    Q4 o;
    o.w = q.w*r.w - dot3(q.v, r.v);
    o.v = add3(add3(scal3(q.w, r.v), scal3(r.w, q.v)), cross3(q.v, r.v));
    return o;
}
__device__ __forceinline__ Q4 qconj(Q4 q){ return { {-q.v.x, -q.v.y, -q.v.z}, q.w }; }
__device__ __forceinline__ F3 qrot(Q4 q, F3 v){
    F3 t = scal3(2.0f, cross3(q.v, v));
    return add3(add3(v, scal3(q.w, t)), cross3(q.v, t));
}
__device__ __forceinline__ F3 so3_log(Q4 q){
    float n = sqrtf(dot3(q.v, q.v));
    float theta = 2.0f * atan2f(n, q.w);
    float k;
    if (n > EPS_Q) k = theta / n;
    else           k = 2.0f / ((fabsf(q.w) > EPS_Q) ? q.w : 1.0f);
    return scal3(k, q.v);
}

// full edge residual; writes 6 floats to o (register array under unroll)
__device__ __forceinline__ void edge_compute(F3 t1, Q4 q1, F3 t2, Q4 q2,
                                             F3 tp, Q4 qp, float* __restrict__ o)
{
    Q4 qi1 = qconj(q1);
    F3 ti1 = scal3(-1.0f, qrot(qi1, t1));
    Q4 qa  = qmul(qi1, q2);
    F3 ta  = add3(ti1, qrot(qi1, t2));

    Q4 qip = qconj(qp);
    F3 tip = scal3(-1.0f, qrot(qip, tp));
    Q4 qe  = qmul(qip, qa);
    F3 te  = add3(tip, qrot(qip, ta));

    F3 phi = so3_log(qe);
    float theta2 = dot3(phi, phi);
    float theta  = sqrtf(theta2);
    float coef;
    if (theta < 1e-4f) {
        coef = 1.0f / 12.0f;
    } else {
        float s, c;
        sincosf(theta, &s, &c);
        coef = 1.0f / theta2 - (1.0f + c) / (2.0f * theta * s);
    }
    F3 pxt = cross3(phi, te);
    F3 tau = add3(sub3(te, scal3(0.5f, pxt)), scal3(coef, cross3(phi, pxt)));

    o[0] = tau.x; o[1] = tau.y; o[2] = tau.z;
    o[3] = phi.x; o[4] = phi.y; o[5] = phi.z;
}

// ---------------- edge kernel: 4 adjacent edges/thread, fully vectorized streams ----
// edges  -> 2x int4   (byte offset 32t, 16-B aligned, NT)
// poses  -> 7x float4 (byte offset 112t, 16-B aligned, NT)
// stores -> 6x float4 (byte offset 96t, 16-B aligned, plain)
// gathers: 16x dwordx4 from padded nodes (32-B records, never span a 64-B line)
__global__ __launch_bounds__(256, 3)
void edge_kernel4(const int*   __restrict__ edges_raw,
                  const float4* __restrict__ pn,
                  const float*  __restrict__ poses_raw,
                  float4*       __restrict__ out4,
                  int ngroups)
{
    int t = blockIdx.x * blockDim.x + threadIdx.x;
    if (t >= ngroups) return;

    const vint4* edges4 = (const vint4*)edges_raw;
    vint4 eA = __builtin_nontemporal_load(edges4 + 2*(size_t)t);
    vint4 eB = __builtin_nontemporal_load(edges4 + 2*(size_t)t + 1);
    int idx[8] = {eA.x, eA.y, eA.z, eA.w, eB.x, eB.y, eB.z, eB.w};

    // 16 independent 16-B gathers in flight
    float4 na[8], nb[8];
    #pragma unroll
    for (int r = 0; r < 8; ++r) {
        na[r] = pn[2*(size_t)idx[r]];
        nb[r] = pn[2*(size_t)idx[r] + 1];
    }

    const vfloat4* poses4 = (const vfloat4*)poses_raw;
    vfloat4 P[7];
    #pragma unroll
    for (int k = 0; k < 7; ++k)
        P[k] = __builtin_nontemporal_load(poses4 + 7*(size_t)t + k);
    const float* pp = (const float*)P;

    float ores[24];
    #pragma unroll
    for (int r = 0; r < 4; ++r) {
        F3 t1 = {na[2*r].x, na[2*r].y, na[2*r].z};
        Q4 q1 = {{na[2*r].w, nb[2*r].x, nb[2*r].y}, nb[2*r].z};
        F3 t2 = {na[2*r+1].x, na[2*r+1].y, na[2*r+1].z};
        Q4 q2 = {{na[2*r+1].w, nb[2*r+1].x, nb[2*r+1].y}, nb[2*r+1].z};
        F3 tp = {pp[7*r+0], pp[7*r+1], pp[7*r+2]};
        Q4 qp = {{pp[7*r+3], pp[7*r+4], pp[7*r+5]}, pp[7*r+6]};
        edge_compute(t1, q1, t2, q2, tp, qp, ores + 6*r);
    }

    float4* o4 = out4 + 6*(size_t)t;
    const float4* ov = (const float4*)ores;
    #pragma unroll
    for (int k = 0; k < 6; ++k) o4[k] = ov[k];
}

// ---------------- node residuals + fused node padding ----------------
// thread m (m < N): pads node m into pn; if m < M also computes residual m.
__global__ void node_pad_kernel(const float*  __restrict__ nodes,
                                float4*       __restrict__ pn,
                                const float*  __restrict__ vels,
                                const float4* __restrict__ imu_drots,
                                const float*  __restrict__ imu_dtrans,
                                const float*  __restrict__ imu_dvels,
                                const float*  __restrict__ dts,
                                float*        __restrict__ out,
                                int M, int N,
                                size_t off_adjvel, size_t off_imurot, size_t off_transvel)
{
    int m = blockIdx.x * blockDim.x + threadIdx.x;
    if (m >= N) return;

    const float* s0 = nodes + 7*(size_t)m;
    float a0=s0[0], a1=s0[1], a2=s0[2], a3=s0[3], a4=s0[4], a5=s0[5], a6=s0[6];
    pn[2*(size_t)m    ] = {a0, a1, a2, a3};
    pn[2*(size_t)m + 1] = {a4, a5, a6, 0.0f};

    if (m >= M) return;

    const float* s1 = nodes + 7*(size_t)(m+1);
    F3 t0 = {a0, a1, a2};  Q4 q0 = {{a3, a4, a5}, a6};
    F3 t1 = {s1[0], s1[1], s1[2]};  Q4 q1 = {{s1[3], s1[4], s1[5]}, s1[6]};

    F3 v0 = {vels[3*(size_t)m],     vels[3*(size_t)m + 1], vels[3*(size_t)m + 2]};
    F3 v1 = {vels[3*(size_t)m + 3], vels[3*(size_t)m + 4], vels[3*(size_t)m + 5]};

    // adjvelerr (L2 = 0.1)
    F3 dvm = {imu_dvels[3*(size_t)m], imu_dvels[3*(size_t)m + 1], imu_dvels[3*(size_t)m + 2]};
    F3 adjv = sub3(dvm, sub3(v1, v0));
    out[off_adjvel + 3*(size_t)m    ] = 0.1f * adjv.x;
    out[off_adjvel + 3*(size_t)m + 1] = 0.1f * adjv.y;
    out[off_adjvel + 3*(size_t)m + 2] = 0.1f * adjv.z;

    // imuroterr (L3 = 1.0)
    float4 drv = imu_drots[m];
    Q4 dr = {{drv.x, drv.y, drv.z}, drv.w};
    Q4 qre = qmul(qconj(dr), qmul(qconj(q0), q1));
    F3 rot = so3_log(qre);
    out[off_imurot + 3*(size_t)m    ] = rot.x;
    out[off_imurot + 3*(size_t)m + 1] = rot.y;
    out[off_imurot + 3*(size_t)m + 2] = rot.z;

    // transvelerr (L4 = 0.1)
    float dt = dts[m];
    F3 dtr = {imu_dtrans[3*(size_t)m], imu_dtrans[3*(size_t)m + 1], imu_dtrans[3*(size_t)m + 2]};
    F3 tv = sub3(sub3(t1, t0), add3(scal3(dt, v0), dtr));
    out[off_transvel + 3*(size_t)m    ] = 0.1f * tv.x;
    out[off_transvel + 3*(size_t)m + 1] = 0.1f * tv.y;
    out[off_transvel + 3*(size_t)m + 2] = 0.1f * tv.z;
}

// ---------------- fallbacks ----------------
// 2 edges/thread padded version (used if E % 4 != 0)
__global__ void edge_kernel2(const int2*   __restrict__ edges,
                             const float4* __restrict__ pn,
                             const float*  __restrict__ poses,
                             float*        __restrict__ out,
                             int E, int half)
{
    int t = blockIdx.x * blockDim.x + threadIdx.x;
    if (t >= half) return;
    int e0 = t;
    int e1 = t + half;
    bool has1 = (e1 < E);
    int e1s = has1 ? e1 : e0;
    int2 ab0 = edges[e0];
    int2 ab1 = edges[e1s];
    float4 na0 = pn[2*(size_t)ab0.x], na1 = pn[2*(size_t)ab0.x + 1];
    float4 nb0 = pn[2*(size_t)ab0.y], nb1 = pn[2*(size_t)ab0.y + 1];
    float4 nc0 = pn[2*(size_t)ab1.x], nc1 = pn[2*(size_t)ab1.x + 1];
    float4 nd0 = pn[2*(size_t)ab1.y], nd1 = pn[2*(size_t)ab1.y + 1];
    const float* p0 = poses + 7*(size_t)e0;
    const float* p1 = poses + 7*(size_t)e1s;
    float pp0[7], pp1[7];
    #pragma unroll
    for (int k = 0; k < 7; ++k) pp0[k] = p0[k];
    #pragma unroll
    for (int k = 0; k < 7; ++k) pp1[k] = p1[k];
    {
        F3 t1 = {na0.x, na0.y, na0.z};  Q4 q1 = {{na0.w, na1.x, na1.y}, na1.z};
        F3 t2 = {nb0.x, nb0.y, nb0.z};  Q4 q2 = {{nb0.w, nb1.x, nb1.y}, nb1.z};
        F3 tp = {pp0[0], pp0[1], pp0[2]}; Q4 qp = {{pp0[3], pp0[4], pp0[5]}, pp0[6]};
        float o[6];
        edge_compute(t1, q1, t2, q2, tp, qp, o);
        float* dst = out + 6*(size_t)e0;
        #pragma unroll
        for (int k = 0; k < 6; ++k) dst[k] = o[k];
    }
    if (has1) {
        F3 t1 = {nc0.x, nc0.y, nc0.z};  Q4 q1 = {{nc0.w, nc1.x, nc1.y}, nc1.z};
        F3 t2 = {nd0.x, nd0.y, nd0.z};  Q4 q2 = {{nd0.w, nd1.x, nd1.y}, nd1.z};
        F3 tp = {pp1[0], pp1[1], pp1[2]}; Q4 qp = {{pp1[3], pp1[4], pp1[5]}, pp1[6]};
        float o[6];
        edge_compute(t1, q1, t2, q2, tp, qp, o);
        float* dst = out + 6*(size_t)e1;
        #pragma unroll
        for (int k = 0; k < 6; ++k) dst[k] = o[k];
    }
}

// unpadded fallback (ws too small)
__global__ void edge_kernel(const int*   __restrict__ edges,
                            const float* __restrict__ nodes,
                            const float* __restrict__ poses,
                            float*       __restrict__ out,
                            int E)
{
    int e = blockIdx.x * blockDim.x + threadIdx.x;
    if (e >= E) return;
    int i = edges[2*(size_t)e];
    int j = edges[2*(size_t)e + 1];
    const float* n1 = nodes + 7*(size_t)i;
    const float* n2 = nodes + 7*(size_t)j;
    const float* p  = poses + 7*(size_t)e;
    F3 t1 = {n1[0], n1[1], n1[2]};  Q4 q1 = {{n1[3], n1[4], n1[5]}, n1[6]};
    F3 t2 = {n2[0], n2[1], n2[2]};  Q4 q2 = {{n2[3], n2[4], n2[5]}, n2[6]};
    F3 tp = {p[0],  p[1],  p[2]};   Q4 qp = {{p[3],  p[4],  p[5]},  p[6]};
    float o[6];
    edge_compute(t1, q1, t2, q2, tp, qp, o);
    float* dst = out + 6*(size_t)e;
    #pragma unroll
    for (int k = 0; k < 6; ++k) dst[k] = o[k];
}

__global__ void node_kernel_raw(const float* __restrict__ nodes,
                                const float* __restrict__ vels,
                                const float* __restrict__ imu_drots,
                                const float* __restrict__ imu_dtrans,
                                const float* __restrict__ imu_dvels,
                                const float* __restrict__ dts,
                                float*       __restrict__ out,
                                int M,
                                size_t off_adjvel, size_t off_imurot, size_t off_transvel)
{
    int m = blockIdx.x * blockDim.x + threadIdx.x;
    if (m >= M) return;
    const float* n0 = nodes + 7*(size_t)m;
    const float* n1 = nodes + 7*(size_t)(m+1);
    F3 t0 = {n0[0], n0[1], n0[2]};  Q4 q0 = {{n0[3], n0[4], n0[5]}, n0[6]};
    F3 t1 = {n1[0], n1[1], n1[2]};  Q4 q1 = {{n1[3], n1[4], n1[5]}, n1[6]};
    F3 v0 = {vels[3*(size_t)m],     vels[3*(size_t)m + 1], vels[3*(size_t)m + 2]};
    F3 v1 = {vels[3*(size_t)m + 3], vels[3*(size_t)m + 4], vels[3*(size_t)m + 5]};
    F3 dvm = {imu_dvels[3*(size_t)m], imu_dvels[3*(size_t)m + 1], imu_dvels[3*(size_t)m + 2]};
    F3 adjv = sub3(dvm, sub3(v1, v0));
    out[off_adjvel + 3*(size_t)m    ] = 0.1f * adjv.x;
    out[off_adjvel + 3*(size_t)m + 1] = 0.1f * adjv.y;
    out[off_adjvel + 3*(size_t)m + 2] = 0.1f * adjv.z;
    Q4 dr = {{imu_drots[4*(size_t)m], imu_drots[4*(size_t)m + 1], imu_drots[4*(size_t)m + 2]},
              imu_drots[4*(size_t)m + 3]};
    Q4 qre = qmul(qconj(dr), qmul(qconj(q0), q1));
    F3 rot = so3_log(qre);
    out[off_imurot + 3*(size_t)m    ] = rot.x;
    out[off_imurot + 3*(size_t)m + 1] = rot.y;
    out[off_imurot + 3*(size_t)m + 2] = rot.z;
    float dt = dts[m];
    F3 dtr = {imu_dtrans[3*(size_t)m], imu_dtrans[3*(size_t)m + 1], imu_dtrans[3*(size_t)m + 2]};
    F3 tv = sub3(sub3(t1, t0), add3(scal3(dt, v0), dtr));
    out[off_transvel + 3*(size_t)m    ] = 0.1f * tv.x;
    out[off_transvel + 3*(size_t)m + 1] = 0.1f * tv.y;
    out[off_transvel + 3*(size_t)m + 2] = 0.1f * tv.z;
}

extern "C" void kernel_launch(void* const* d_in, const int* in_sizes, int n_in,
                              void* d_out, int out_size, void* d_ws, size_t ws_size,
                              hipStream_t stream) {
    const int*   edges      = (const int*)  d_in[0];
    const float* nodes      = (const float*)d_in[1];
    const float* vels       = (const float*)d_in[2];
    const float* poses      = (const float*)d_in[3];
    const float* imu_drots  = (const float*)d_in[4];
    const float* imu_dtrans = (const float*)d_in[5];
    const float* imu_dvels  = (const float*)d_in[6];
    const float* dts        = (const float*)d_in[7];
    float* out = (float*)d_out;

    const int E = in_sizes[0] / 2;
    const int N = in_sizes[1] / 7;
    const int M = in_sizes[7];

    const size_t off_adjvel   = 6*(size_t)E;
    const size_t off_imurot   = off_adjvel + 3*(size_t)M;
    const size_t off_transvel = off_imurot + 3*(size_t)M;

    const int BLK = 256;
    const size_t need = 2 * (size_t)N * sizeof(float4);   // 32 B per node

    if (ws_size >= need) {
        float4* pn = (float4*)d_ws;
        // node residuals + padding in one pass (pad must precede edge gathers)
        node_pad_kernel<<<(N + BLK - 1) / BLK, BLK, 0, stream>>>(
            nodes, pn, vels, (const float4*)imu_drots, imu_dtrans, imu_dvels, dts,
            out, M, N, off_adjvel, off_imurot, off_transvel);
        if ((E & 3) == 0) {
            const int ngroups = E / 4;
            edge_kernel4<<<(ngroups + BLK - 1) / BLK, BLK, 0, stream>>>(
                edges, pn, poses, (float4*)out, ngroups);
        } else {
            const int half = (E + 1) / 2;
            edge_kernel2<<<(half + BLK - 1) / BLK, BLK, 0, stream>>>(
                (const int2*)edges, pn, poses, out, E, half);
        }
    } else {
        edge_kernel<<<(E + BLK - 1) / BLK, BLK, 0, stream>>>(edges, nodes, poses, out, E);
        node_kernel_raw<<<(M + BLK - 1) / BLK, BLK, 0, stream>>>(nodes, vels, imu_drots, imu_dtrans,
                                                                 imu_dvels, dts, out, M,
                                                                 off_adjvel, off_imurot, off_transvel);
    }
}